// Round 10
// baseline (535.355 us; speedup 1.0000x reference)
//
#include <hip/hip_runtime.h>
#include <float.h>

#define M_TOT 16384
#define H_DIM 2048
#define NV    5000
#define NVP1  5001
#define N_PAD 5120
#define POOL_ROW_STRIDE (33 * 2048)
#define POOL_LAYER_OFF  (16 * 2048)

#define BM 256
#define BN 128
#define BKB 128                 // K-tile in BYTES per row (=128 int8 elems)
#define KITER (H_DIM / 128)     // 16
#define NTM (M_TOT / BM)        // 64
#define NTN (N_PAD / BN)        // 40
#define NWG (NTM * NTN)         // 2560 = 8 * 320
#define NCHUNK (NTN * 2)        // 80 column-chunks of 64
#define MARGIN 0.2f

#define XMAX 6.0f
#define WMAX 0.12f
#define SF   ((XMAX / 127.0f) * (WMAX / 127.0f))

typedef __attribute__((ext_vector_type(4))) int i32x4;
typedef unsigned long long ull;

__device__ __forceinline__ void load16_to_lds(const void* g, void* l) {
    __builtin_amdgcn_global_load_lds((const __attribute__((address_space(1))) void*)g,
                                     (__attribute__((address_space(3))) void*)l, 16, 0, 0);
}

__device__ __forceinline__ int q127(float v, float inv_step, float vmax) {
    float c = fminf(fmaxf(v, -vmax), vmax);
    return (int)rintf(c * inv_step);
}

// sortable u64 key: high 32 = monotone-mapped float, low 32 = ~col (lower col wins ties)
__device__ __forceinline__ int key_col(ull k) { return (int)(~(unsigned)(k & 0xffffffffu)); }
__device__ __forceinline__ float key_val(ull k) {
    unsigned kk = (unsigned)(k >> 32);
    unsigned u = (kk & 0x80000000u) ? (kk ^ 0x80000000u) : ~kk;
    return __uint_as_float(u);
}

// ---------------------------------------------------------------------------
// fused fp32 -> int8 quantize (x clamp +-6, w clamp +-0.12, zero-padded)
// ---------------------------------------------------------------------------
#define XCNT (M_TOT * H_DIM / 4)
#define WCNT (N_PAD * H_DIM / 4)
__global__ __launch_bounds__(256) void quant_kernel(const float* __restrict__ x,
                                                    const float* __restrict__ gw,
                                                    unsigned* __restrict__ xq,
                                                    unsigned* __restrict__ wq) {
    const int stride = gridDim.x * blockDim.x;
    const float xinv = 127.0f / XMAX;
    const float winv = 127.0f / WMAX;
    for (int i = blockIdx.x * blockDim.x + threadIdx.x; i < XCNT + WCNT; i += stride) {
        if (i < XCNT) {
            float4 v = ((const float4*)x)[i];
            unsigned p = ((unsigned)(q127(v.x, xinv, XMAX) & 0xff)) |
                         ((unsigned)(q127(v.y, xinv, XMAX) & 0xff) << 8) |
                         ((unsigned)(q127(v.z, xinv, XMAX) & 0xff) << 16) |
                         ((unsigned)(q127(v.w, xinv, XMAX) & 0xff) << 24);
            xq[i] = p;
        } else {
            const int j = i - XCNT;
            const int row = j >> 9;
            unsigned p = 0;
            if (row < NVP1) {
                float4 v = ((const float4*)gw)[j];
                p = ((unsigned)(q127(v.x, winv, WMAX) & 0xff)) |
                    ((unsigned)(q127(v.y, winv, WMAX) & 0xff) << 8) |
                    ((unsigned)(q127(v.z, winv, WMAX) & 0xff) << 16) |
                    ((unsigned)(q127(v.w, winv, WMAX) & 0xff) << 24);
            }
            wq[j] = p;
        }
    }
}

// ---------------------------------------------------------------------------
// int8 MFMA GEMM (xq @ wq^T, exact i32 accum) fused with per-64-col top-3.
// R8-proven schedule (single-buffer, __syncthreads), scaled to BM=256 /
// 8 waves: -25% L2 fetch per output, 16 waves/CU (2 blocks x 8).
// ---------------------------------------------------------------------------
__global__ __launch_bounds__(512, 4)
void gemm_top3_kernel(const unsigned char* __restrict__ xq,
                      const unsigned char* __restrict__ wq,
                      const float* __restrict__ gb,
                      ull* __restrict__ pk1, ull* __restrict__ pk2, ull* __restrict__ pk3)
{
    __shared__ __align__(16) char albuf[BM * BKB];   // 32 KB, row stride 128B
    __shared__ __align__(16) char blbuf[BN * BKB];   // 16 KB
    __shared__ float bl[BN];

    const int t    = threadIdx.x;
    const int w    = t >> 6;          // 0..7
    const int lane = t & 63;
    const int wm   = w >> 1;          // 0..3 (64-row band)
    const int wn   = w & 1;           // 0..1 (64-col half)

    // L2-banded XCD mapping: 2560 = 8 xcd * 5 nt * 64 mt
    const int bid0  = blockIdx.x;
    const int xcd   = bid0 & 7;
    const int local = bid0 >> 3;          // 0..319
    const int nt    = xcd * 5 + (local % 5);
    const int mt    = local / 5;
    const int m0    = mt * BM;
    const int n0    = nt * BN;

    if (t < BN) bl[t] = (n0 + t < NVP1) ? gb[n0 + t] : 0.0f;

    // staging: wave w stages A rows w*32..+31 (4 insts) and B rows w*16..+15 (2 insts)
    const int srow  = lane >> 3;
    const int sslot = lane & 7;
    const char* agp[4];
    const char* bgp[2];
#pragma unroll
    for (int p = 0; p < 4; ++p) {
        const int r = w * 32 + p * 8 + srow;
        agp[p] = (const char*)xq + (size_t)(m0 + r) * H_DIM + ((sslot ^ (r & 7)) << 4);
    }
#pragma unroll
    for (int p = 0; p < 2; ++p) {
        const int r = w * 16 + p * 8 + srow;
        bgp[p] = (const char*)wq + (size_t)(n0 + r) * H_DIM + ((sslot ^ (r & 7)) << 4);
    }

    i32x4 acc[4][4];
    const i32x4 z4 = {0, 0, 0, 0};
#pragma unroll
    for (int i = 0; i < 4; ++i)
#pragma unroll
        for (int j = 0; j < 4; ++j) acc[i][j] = z4;

    for (int kt = 0; kt < KITER; ++kt) {
        __syncthreads();
#pragma unroll
        for (int p = 0; p < 4; ++p)
            load16_to_lds(agp[p] + kt * BKB, albuf + (w * 32 + p * 8) * 128);
#pragma unroll
        for (int p = 0; p < 2; ++p)
            load16_to_lds(bgp[p] + kt * BKB, blbuf + (w * 16 + p * 8) * 128);
        __syncthreads();

#pragma unroll
        for (int kk = 0; kk < 2; ++kk) {
            i32x4 af[4], bfr[4];
#pragma unroll
            for (int f = 0; f < 4; ++f) {
                const int ra = wm * 64 + f * 16 + (lane & 15);
                const int sa = (kk * 4 + (lane >> 4)) ^ (ra & 7);
                af[f] = *(const i32x4*)(albuf + ra * 128 + sa * 16);
                const int rb = wn * 64 + f * 16 + (lane & 15);
                const int sb = (kk * 4 + (lane >> 4)) ^ (rb & 7);
                bfr[f] = *(const i32x4*)(blbuf + rb * 128 + sb * 16);
            }
#pragma unroll
            for (int i = 0; i < 4; ++i)
#pragma unroll
                for (int j = 0; j < 4; ++j)
                    acc[i][j] = __builtin_amdgcn_mfma_i32_16x16x64_i8(af[i], bfr[j], acc[i][j], 0, 0, 0);
        }
    }

    // Epilogue: u64-packed top-3 per row, 16-lane shuffle reduce.
    const int g  = lane >> 4;
    const int cl = lane & 15;
    const int pc = nt * 2 + wn;
#pragma unroll
    for (int fi = 0; fi < 4; ++fi) {
#pragma unroll
        for (int q = 0; q < 4; ++q) {
            ull k1 = 0, k2 = 0, k3 = 0;
#pragma unroll
            for (int fj = 0; fj < 4; ++fj) {
                const int cin = wn * 64 + fj * 16 + cl;
                const int col = n0 + cin;
                const float v = (float)acc[fi][fj][q] * SF + bl[cin];
                unsigned u = __float_as_uint(v);
                unsigned k32 = u ^ ((u >> 31) ? 0xFFFFFFFFu : 0x80000000u);
                int ecol = col;
                if (col >= NVP1) { k32 = 0u; ecol = 0x7fffffff; }
                const ull k = ((ull)k32 << 32) | (unsigned)(~ecol);
                if (k > k1)      { k3 = k2; k2 = k1; k1 = k; }
                else if (k > k2) { k3 = k2; k2 = k; }
                else if (k > k3) { k3 = k; }
            }
#pragma unroll
            for (int m = 1; m < 16; m <<= 1) {
                const ull o1 = __shfl_xor(k1, m, 64);
                const ull o2 = __shfl_xor(k2, m, 64);
                const ull o3 = __shfl_xor(k3, m, 64);
                const bool a = k1 >= o1;
                const ull w2 = a ? k2 : o2, w3 = a ? k3 : o3;
                const ull l1 = a ? o1 : k1, l2 = a ? o2 : k2;
                const bool b = w2 >= l1;
                const ull n1 = a ? k1 : o1;
                const ull n2 = b ? w2 : l1;
                const ull n3 = b ? (w3 >= l1 ? w3 : l1) : (w2 >= l2 ? w2 : l2);
                k1 = n1; k2 = n2; k3 = n3;
            }
            if (cl == 0) {
                const int row = m0 + wm * 64 + fi * 16 + g * 4 + q;
                pk1[(size_t)pc * M_TOT + row] = k1;
                pk2[(size_t)pc * M_TOT + row] = k2;
                pk3[(size_t)pc * M_TOT + row] = k3;
            }
        }
    }
}

// ---------------------------------------------------------------------------
// Merge 80 chunk-partials (3 u64 keys each); flag ambiguous tokens.
// ---------------------------------------------------------------------------
__device__ __forceinline__ void ins8k(ull k, ull tk[8]) {
#pragma unroll
    for (int s = 0; s < 8; ++s) {
        const bool b = k > tk[s];
        const ull nv = b ? k : tk[s];
        k = b ? tk[s] : k;
        tk[s] = nv;
    }
}

__global__ __launch_bounds__(256)
void merge_kernel(const ull* __restrict__ pk1, const ull* __restrict__ pk2,
                  const ull* __restrict__ pk3,
                  int* __restrict__ fidx, int* __restrict__ counter, int* __restrict__ jobs)
{
    const int token = blockIdx.x * 256 + threadIdx.x;
    ull tk[8];
#pragma unroll
    for (int s = 0; s < 8; ++s) tk[s] = 0;
    for (int pc = 0; pc < NCHUNK; ++pc) {
        ins8k(pk1[(size_t)pc * M_TOT + token], tk);
        ins8k(pk2[(size_t)pc * M_TOT + token], tk);
        ins8k(pk3[(size_t)pc * M_TOT + token], tk);
    }
    const float v0 = key_val(tk[0]);
    int cols[8];
    int cnt = 0;
#pragma unroll
    for (int s = 0; s < 8; ++s) {
        int c = key_col(tk[s]);
        if ((unsigned)c > (unsigned)NV) c = 0x7fffffff;
        else if (!(key_val(tk[s]) >= v0 - MARGIN)) c = 0x7fffffff;
        cols[s] = c;
        if (c != 0x7fffffff) cnt++;
    }
    fidx[token] = key_col(tk[0]);
    if (cnt > 1) {
        const int slot = atomicAdd(counter, 1);
        int* jp = jobs + (size_t)slot * 12;
        jp[0] = token;
        jp[1] = cnt;
#pragma unroll
        for (int s = 0; s < 8; ++s) jp[2 + s] = cols[s];
    }
}

// ---------------------------------------------------------------------------
// Exact fp32 rescore (<=8 dots per flagged token). x-row staged in LDS once
// (was re-read 8x from global).
// ---------------------------------------------------------------------------
__global__ __launch_bounds__(256)
void rescore_kernel(const float* __restrict__ x, const float* __restrict__ gw,
                    const float* __restrict__ gb, const int* __restrict__ jobs,
                    const int* __restrict__ counter, int* __restrict__ fidx)
{
    __shared__ float xl[H_DIM];
    __shared__ float sv[8];
    __shared__ int   si[8];
    __shared__ int   sjob[10];
    const int njobs = counter[0];
    const int t = threadIdx.x;
    for (int j = blockIdx.x; j < njobs; j += gridDim.x) {
        if (t < 10) sjob[t] = jobs[(size_t)j * 12 + t];
        __syncthreads();
        const int token = sjob[0];
        // stage x row: 256 threads x 2 float4
        {
            const float4* xr = (const float4*)(x + (size_t)token * H_DIM);
            ((float4*)xl)[t]       = xr[t];
            ((float4*)xl)[t + 256] = xr[t + 256];
        }
        __syncthreads();
        const int g  = t >> 5;
        const int sl = t & 31;
        const int cand = sjob[2 + g];
        float v = -FLT_MAX;
        if (cand <= NV) {
            const float4* wr = (const float4*)(gw + (size_t)cand * H_DIM);
            float s = 0.f;
            for (int k = sl; k < H_DIM / 4; k += 32) {
                const float4 a = ((const float4*)xl)[k];
                const float4 b = wr[k];
                s = fmaf(a.x, b.x, s); s = fmaf(a.y, b.y, s);
                s = fmaf(a.z, b.z, s); s = fmaf(a.w, b.w, s);
            }
#pragma unroll
            for (int m = 1; m < 32; m <<= 1) s += __shfl_xor(s, m, 64);
            v = s + gb[cand];
        }
        if (sl == 0) { sv[g] = v; si[g] = (cand <= NV) ? cand : 0x7fffffff; }
        __syncthreads();
        if (t == 0) {
            float bv = sv[0]; int bi = si[0];
#pragma unroll
            for (int q = 1; q < 8; ++q)
                if (sv[q] > bv || (sv[q] == bv && si[q] < bi)) { bv = sv[q]; bi = si[q]; }
            fidx[token] = bi;
        }
        __syncthreads();
    }
}

// ---------------------------------------------------------------------------
// Final gather
// ---------------------------------------------------------------------------
__global__ __launch_bounds__(256)
void gather_kernel(const float* __restrict__ x, const float* __restrict__ pool,
                   const int* __restrict__ fidx, float* __restrict__ out)
{
    const int token = blockIdx.x;
    const int idx = fidx[token];
    const float4* src;
    if (idx == NV) {
        src = (const float4*)(x + (size_t)token * H_DIM);
    } else {
        const int safe = (idx < NV) ? idx : (NV - 1);
        src = (const float4*)(pool + (size_t)safe * POOL_ROW_STRIDE + POOL_LAYER_OFF);
    }
    float4* dst = (float4*)(out + (size_t)token * H_DIM);
    dst[threadIdx.x]       = src[threadIdx.x];
    dst[threadIdx.x + 256] = src[threadIdx.x + 256];
}

extern "C" void kernel_launch(void* const* d_in, const int* in_sizes, int n_in,
                              void* d_out, int out_size, void* d_ws, size_t ws_size,
                              hipStream_t stream)
{
    const float* x    = (const float*)d_in[0];
    const float* gw   = (const float*)d_in[1];
    const float* gb   = (const float*)d_in[2];
    const float* pool = (const float*)d_in[3];
    float* out = (float*)d_out;

    // x_q parked in d_out (33.5 MB of 134 MB; gather fully overwrites d_out later)
    unsigned char* xq = (unsigned char*)d_out;

    char* wsb = (char*)d_ws;
    unsigned char* wq = (unsigned char*)wsb;                           // 10.5 MB
    size_t off = (size_t)N_PAD * H_DIM;
    ull* pk1 = (ull*)(wsb + off); off += (size_t)NCHUNK * M_TOT * 8;   // 10.5 MB
    ull* pk2 = (ull*)(wsb + off); off += (size_t)NCHUNK * M_TOT * 8;
    ull* pk3 = (ull*)(wsb + off); off += (size_t)NCHUNK * M_TOT * 8;
    int* fidx = (int*)(wsb + off); off += (size_t)M_TOT * 4;
    int* counter = (int*)(wsb + off); off += 256;
    int* jobs = (int*)(wsb + off);                                     // 768 KB

    hipMemsetAsync(counter, 0, sizeof(int), stream);

    quant_kernel<<<3072, 256, 0, stream>>>(x, gw, (unsigned*)xq, (unsigned*)wq);

    gemm_top3_kernel<<<NWG, 512, 0, stream>>>(xq, wq, gb, pk1, pk2, pk3);

    merge_kernel<<<M_TOT / 256, 256, 0, stream>>>(pk1, pk2, pk3, fidx, counter, jobs);
    rescore_kernel<<<1024, 256, 0, stream>>>(x, gw, gb, jobs, counter, fidx);
    gather_kernel<<<M_TOT, 256, 0, stream>>>(x, pool, fidx, out);
}

// Round 11
// 372.135 us; speedup vs baseline: 1.4386x; 1.4386x over previous
//
#include <hip/hip_runtime.h>
#include <float.h>

#define M_TOT 16384
#define H_DIM 2048
#define NV    5000
#define NVP1  5001
#define N_PAD 5120
#define POOL_ROW_STRIDE (33 * 2048)
#define POOL_LAYER_OFF  (16 * 2048)

#define BM 128
#define BN 128
#define BKB 128                 // K-tile in BYTES per row (=128 int8 elems)
#define KITER (H_DIM / 128)     // 16
#define NTM (M_TOT / BM)        // 128
#define NTN (N_PAD / BN)        // 40
#define NWG (NTM * NTN)         // 5120
#define NCHUNK (NTN * 2)        // 80 column-chunks of 64
#define MARGIN 0.22f

#define XMAX 6.0f
#define WMAX 0.12f
#define SF   ((XMAX / 127.0f) * (WMAX / 127.0f))

typedef __attribute__((ext_vector_type(4))) int i32x4;

__device__ __forceinline__ void load16_to_lds(const void* g, void* l) {
    __builtin_amdgcn_global_load_lds((const __attribute__((address_space(1))) void*)g,
                                     (__attribute__((address_space(3))) void*)l, 16, 0, 0);
}

__device__ __forceinline__ int q127(float v, float inv_step, float vmax) {
    float c = fminf(fmaxf(v, -vmax), vmax);
    return (int)rintf(c * inv_step);
}

// u32 key: top 19 bits = monotone fp32 prefix (floored), low 13 = 8191-col
// (lower col wins ties). key==0 <=> invalid (real keys have low13 >= 3071).
__device__ __forceinline__ int key_col32(unsigned k) { return 8191 - (int)(k & 8191u); }
__device__ __forceinline__ float key_val32(unsigned k) {
    unsigned m = k & 0xFFFFE000u;
    unsigned u = (m & 0x80000000u) ? (m ^ 0x80000000u) : ~m;
    return __uint_as_float(u);
}

// ---------------------------------------------------------------------------
// fused fp32 -> int8 quantize (x clamp +-6, w clamp +-0.12, zero-padded)
// ---------------------------------------------------------------------------
#define XCNT (M_TOT * H_DIM / 4)
#define WCNT (N_PAD * H_DIM / 4)
__global__ __launch_bounds__(256) void quant_kernel(const float* __restrict__ x,
                                                    const float* __restrict__ gw,
                                                    unsigned* __restrict__ xq,
                                                    unsigned* __restrict__ wq) {
    const int stride = gridDim.x * blockDim.x;
    const float xinv = 127.0f / XMAX;
    const float winv = 127.0f / WMAX;
    for (int i = blockIdx.x * blockDim.x + threadIdx.x; i < XCNT + WCNT; i += stride) {
        if (i < XCNT) {
            float4 v = ((const float4*)x)[i];
            unsigned p = ((unsigned)(q127(v.x, xinv, XMAX) & 0xff)) |
                         ((unsigned)(q127(v.y, xinv, XMAX) & 0xff) << 8) |
                         ((unsigned)(q127(v.z, xinv, XMAX) & 0xff) << 16) |
                         ((unsigned)(q127(v.w, xinv, XMAX) & 0xff) << 24);
            xq[i] = p;
        } else {
            const int j = i - XCNT;
            const int row = j >> 9;
            unsigned p = 0;
            if (row < NVP1) {
                float4 v = ((const float4*)gw)[j];
                p = ((unsigned)(q127(v.x, winv, WMAX) & 0xff)) |
                    ((unsigned)(q127(v.y, winv, WMAX) & 0xff) << 8) |
                    ((unsigned)(q127(v.z, winv, WMAX) & 0xff) << 16) |
                    ((unsigned)(q127(v.w, winv, WMAX) & 0xff) << 24);
            }
            wq[j] = p;
        }
    }
}

// ---------------------------------------------------------------------------
// int8 MFMA GEMM (xq @ wq^T, exact i32 accum) fused with per-64-col top-3.
// R7-proven loop (single-buffer, __syncthreads, 3 blocks/CU, L2-banded XCD
// mapping). New: u32-packed keys in the epilogue (half the shuffle work).
// ---------------------------------------------------------------------------
__global__ __launch_bounds__(256, 3)
void gemm_top3_kernel(const unsigned char* __restrict__ xq,
                      const unsigned char* __restrict__ wq,
                      const float* __restrict__ gb,
                      unsigned* __restrict__ pk1, unsigned* __restrict__ pk2,
                      unsigned* __restrict__ pk3)
{
    __shared__ __align__(16) char albuf[BM * BKB];   // 16 KB, row stride 128B
    __shared__ __align__(16) char blbuf[BN * BKB];   // 16 KB
    __shared__ float bl[BN];

    const int t    = threadIdx.x;
    const int w    = t >> 6;
    const int lane = t & 63;
    const int wm   = w >> 1;
    const int wn   = w & 1;

    // L2-banded XCD mapping: 5120 = 8 xcd * 5 nt * 128 mt
    const int bid0  = blockIdx.x;
    const int xcd   = bid0 & 7;
    const int local = bid0 >> 3;
    const int nt    = xcd * 5 + (local % 5);
    const int mt    = local / 5;
    const int m0    = mt * BM;
    const int n0    = nt * BN;

    if (t < BN) bl[t] = (n0 + t < NVP1) ? gb[n0 + t] : 0.0f;

    const int srow  = lane >> 3;
    const int sslot = lane & 7;
    const char* agp[4];
    const char* bgp[4];
#pragma unroll
    for (int p = 0; p < 4; ++p) {
        const int r = w * 32 + p * 8 + srow;
        agp[p] = (const char*)xq + (size_t)(m0 + r) * H_DIM + ((sslot ^ (r & 7)) << 4);
        bgp[p] = (const char*)wq + (size_t)(n0 + r) * H_DIM + ((sslot ^ (r & 7)) << 4);
    }

    i32x4 acc[4][4];
    const i32x4 z4 = {0, 0, 0, 0};
#pragma unroll
    for (int i = 0; i < 4; ++i)
#pragma unroll
        for (int j = 0; j < 4; ++j) acc[i][j] = z4;

    for (int kt = 0; kt < KITER; ++kt) {
        __syncthreads();
#pragma unroll
        for (int p = 0; p < 4; ++p) {
            load16_to_lds(agp[p] + kt * BKB, albuf + w * 4096 + p * 1024);
            load16_to_lds(bgp[p] + kt * BKB, blbuf + w * 4096 + p * 1024);
        }
        __syncthreads();

#pragma unroll
        for (int kk = 0; kk < 2; ++kk) {
            i32x4 af[4], bfr[4];
#pragma unroll
            for (int f = 0; f < 4; ++f) {
                const int ra = wm * 64 + f * 16 + (lane & 15);
                const int sa = (kk * 4 + (lane >> 4)) ^ (ra & 7);
                af[f] = *(const i32x4*)(albuf + ra * 128 + sa * 16);
                const int rb = wn * 64 + f * 16 + (lane & 15);
                const int sb = (kk * 4 + (lane >> 4)) ^ (rb & 7);
                bfr[f] = *(const i32x4*)(blbuf + rb * 128 + sb * 16);
            }
#pragma unroll
            for (int i = 0; i < 4; ++i)
#pragma unroll
                for (int j = 0; j < 4; ++j)
                    acc[i][j] = __builtin_amdgcn_mfma_i32_16x16x64_i8(af[i], bfr[j], acc[i][j], 0, 0, 0);
        }
    }

    // Epilogue: u32-packed top-3 per row, 16-lane shuffle reduce.
    const int g  = lane >> 4;
    const int cl = lane & 15;
    const int pc = nt * 2 + wn;
#pragma unroll
    for (int fi = 0; fi < 4; ++fi) {
#pragma unroll
        for (int q = 0; q < 4; ++q) {
            unsigned k1 = 0, k2 = 0, k3 = 0;
#pragma unroll
            for (int fj = 0; fj < 4; ++fj) {
                const int cin = wn * 64 + fj * 16 + cl;
                const int col = n0 + cin;
                const float v = (float)acc[fi][fj][q] * SF + bl[cin];
                unsigned u = __float_as_uint(v);
                unsigned mm = u ^ ((u >> 31) ? 0xFFFFFFFFu : 0x80000000u);
                const unsigned k = (col < NVP1)
                    ? ((mm & 0xFFFFE000u) | (8191u - (unsigned)col)) : 0u;
                if (k > k1)      { k3 = k2; k2 = k1; k1 = k; }
                else if (k > k2) { k3 = k2; k2 = k; }
                else if (k > k3) { k3 = k; }
            }
#pragma unroll
            for (int ms = 1; ms < 16; ms <<= 1) {
                const unsigned o1 = __shfl_xor(k1, ms, 64);
                const unsigned o2 = __shfl_xor(k2, ms, 64);
                const unsigned o3 = __shfl_xor(k3, ms, 64);
                const bool a = k1 >= o1;
                const unsigned w2 = a ? k2 : o2, w3 = a ? k3 : o3;
                const unsigned l1 = a ? o1 : k1, l2 = a ? o2 : k2;
                const bool b = w2 >= l1;
                const unsigned n1 = a ? k1 : o1;
                const unsigned n2 = b ? w2 : l1;
                const unsigned n3 = b ? (w3 >= l1 ? w3 : l1) : (w2 >= l2 ? w2 : l2);
                k1 = n1; k2 = n2; k3 = n3;
            }
            if (cl == 0) {
                const int row = m0 + wm * 64 + fi * 16 + g * 4 + q;
                pk1[(size_t)pc * M_TOT + row] = k1;
                pk2[(size_t)pc * M_TOT + row] = k2;
                pk3[(size_t)pc * M_TOT + row] = k3;
            }
        }
    }
}

// ---------------------------------------------------------------------------
// Merge 80 chunk-partials (3 u32 keys each); flag ambiguous tokens.
// ---------------------------------------------------------------------------
__device__ __forceinline__ void ins8k(unsigned k, unsigned tk[8]) {
#pragma unroll
    for (int s = 0; s < 8; ++s) {
        const bool b = k > tk[s];
        const unsigned nv = b ? k : tk[s];
        k = b ? tk[s] : k;
        tk[s] = nv;
    }
}

__global__ __launch_bounds__(256)
void merge_kernel(const unsigned* __restrict__ pk1, const unsigned* __restrict__ pk2,
                  const unsigned* __restrict__ pk3,
                  int* __restrict__ fidx, int* __restrict__ counter, int* __restrict__ jobs)
{
    const int token = blockIdx.x * 256 + threadIdx.x;
    unsigned tk[8];
#pragma unroll
    for (int s = 0; s < 8; ++s) tk[s] = 0;
    for (int pc = 0; pc < NCHUNK; ++pc) {
        ins8k(pk1[(size_t)pc * M_TOT + token], tk);
        ins8k(pk2[(size_t)pc * M_TOT + token], tk);
        ins8k(pk3[(size_t)pc * M_TOT + token], tk);
    }
    const float v0 = key_val32(tk[0]);
    int cols[8];
    int cnt = 0;
#pragma unroll
    for (int s = 0; s < 8; ++s) {
        int c = (tk[s] == 0u) ? 0x7fffffff : key_col32(tk[s]);
        if (c != 0x7fffffff && (unsigned)c > (unsigned)NV) c = 0x7fffffff;
        else if (c != 0x7fffffff && !(key_val32(tk[s]) >= v0 - MARGIN)) c = 0x7fffffff;
        cols[s] = c;
        if (c != 0x7fffffff) cnt++;
    }
    fidx[token] = key_col32(tk[0]);
    if (cnt > 1) {
        const int slot = atomicAdd(counter, 1);
        int* jp = jobs + (size_t)slot * 12;
        jp[0] = token;
        jp[1] = cnt;
#pragma unroll
        for (int s = 0; s < 8; ++s) jp[2 + s] = cols[s];
    }
}

// ---------------------------------------------------------------------------
// Exact fp32 rescore (<=8 dots per flagged token); x-row staged in LDS once.
// ---------------------------------------------------------------------------
__global__ __launch_bounds__(256)
void rescore_kernel(const float* __restrict__ x, const float* __restrict__ gw,
                    const float* __restrict__ gb, const int* __restrict__ jobs,
                    const int* __restrict__ counter, int* __restrict__ fidx)
{
    __shared__ float xl[H_DIM];
    __shared__ float sv[8];
    __shared__ int   si[8];
    __shared__ int   sjob[10];
    const int njobs = counter[0];
    const int t = threadIdx.x;
    for (int j = blockIdx.x; j < njobs; j += gridDim.x) {
        if (t < 10) sjob[t] = jobs[(size_t)j * 12 + t];
        __syncthreads();
        const int token = sjob[0];
        {
            const float4* xr = (const float4*)(x + (size_t)token * H_DIM);
            ((float4*)xl)[t]       = xr[t];
            ((float4*)xl)[t + 256] = xr[t + 256];
        }
        __syncthreads();
        const int g  = t >> 5;
        const int sl = t & 31;
        const int cand = sjob[2 + g];
        float v = -FLT_MAX;
        if (cand <= NV) {
            const float4* wr = (const float4*)(gw + (size_t)cand * H_DIM);
            float s = 0.f;
            for (int k = sl; k < H_DIM / 4; k += 32) {
                const float4 a = ((const float4*)xl)[k];
                const float4 b = wr[k];
                s = fmaf(a.x, b.x, s); s = fmaf(a.y, b.y, s);
                s = fmaf(a.z, b.z, s); s = fmaf(a.w, b.w, s);
            }
#pragma unroll
            for (int m = 1; m < 32; m <<= 1) s += __shfl_xor(s, m, 64);
            v = s + gb[cand];
        }
        if (sl == 0) { sv[g] = v; si[g] = (cand <= NV) ? cand : 0x7fffffff; }
        __syncthreads();
        if (t == 0) {
            float bv = sv[0]; int bi = si[0];
#pragma unroll
            for (int q = 1; q < 8; ++q)
                if (sv[q] > bv || (sv[q] == bv && si[q] < bi)) { bv = sv[q]; bi = si[q]; }
            fidx[token] = bi;
        }
        __syncthreads();
    }
}

// ---------------------------------------------------------------------------
// Final gather
// ---------------------------------------------------------------------------
__global__ __launch_bounds__(256)
void gather_kernel(const float* __restrict__ x, const float* __restrict__ pool,
                   const int* __restrict__ fidx, float* __restrict__ out)
{
    const int token = blockIdx.x;
    const int idx = fidx[token];
    const float4* src;
    if (idx == NV) {
        src = (const float4*)(x + (size_t)token * H_DIM);
    } else {
        const int safe = (idx < NV) ? idx : (NV - 1);
        src = (const float4*)(pool + (size_t)safe * POOL_ROW_STRIDE + POOL_LAYER_OFF);
    }
    float4* dst = (float4*)(out + (size_t)token * H_DIM);
    dst[threadIdx.x]       = src[threadIdx.x];
    dst[threadIdx.x + 256] = src[threadIdx.x + 256];
}

extern "C" void kernel_launch(void* const* d_in, const int* in_sizes, int n_in,
                              void* d_out, int out_size, void* d_ws, size_t ws_size,
                              hipStream_t stream)
{
    const float* x    = (const float*)d_in[0];
    const float* gw   = (const float*)d_in[1];
    const float* gb   = (const float*)d_in[2];
    const float* pool = (const float*)d_in[3];
    float* out = (float*)d_out;

    // x_q parked in d_out (33.5 MB of 134 MB; gather fully overwrites d_out later)
    unsigned char* xq = (unsigned char*)d_out;

    char* wsb = (char*)d_ws;
    unsigned char* wq = (unsigned char*)wsb;                               // 10.5 MB
    size_t off = (size_t)N_PAD * H_DIM;
    unsigned* pk1 = (unsigned*)(wsb + off); off += (size_t)NCHUNK * M_TOT * 4; // 5.24 MB
    unsigned* pk2 = (unsigned*)(wsb + off); off += (size_t)NCHUNK * M_TOT * 4;
    unsigned* pk3 = (unsigned*)(wsb + off); off += (size_t)NCHUNK * M_TOT * 4;
    int* fidx = (int*)(wsb + off); off += (size_t)M_TOT * 4;
    int* counter = (int*)(wsb + off); off += 256;
    int* jobs = (int*)(wsb + off);                                         // 768 KB

    hipMemsetAsync(counter, 0, sizeof(int), stream);

    quant_kernel<<<3072, 256, 0, stream>>>(x, gw, (unsigned*)xq, (unsigned*)wq);

    gemm_top3_kernel<<<NWG, 256, 0, stream>>>(xq, wq, gb, pk1, pk2, pk3);

    merge_kernel<<<M_TOT / 256, 256, 0, stream>>>(pk1, pk2, pk3, fidx, counter, jobs);
    rescore_kernel<<<1024, 256, 0, stream>>>(x, gw, gb, jobs, counter, fidx);
    gather_kernel<<<M_TOT, 256, 0, stream>>>(x, pool, fidx, out);
}

// Round 12
// 352.468 us; speedup vs baseline: 1.5189x; 1.0558x over previous
//
#include <hip/hip_runtime.h>
#include <float.h>

#define M_TOT 16384
#define H_DIM 2048
#define NV    5000
#define NVP1  5001
#define N_PAD 5120
#define POOL_ROW_STRIDE (33 * 2048)
#define POOL_LAYER_OFF  (16 * 2048)

#define BM 128
#define BN 128
#define BKB 128                 // K-tile in BYTES per row (=128 int8 elems)
#define KITER (H_DIM / 128)     // 16
#define NTM (M_TOT / BM)        // 128
#define NTN (N_PAD / BN)        // 40
#define NWG (NTM * NTN)         // 5120
#define NCHUNK (NTN * 2)        // 80 column-chunks of 64
#define MARGIN 0.16f

#define XMAX 6.0f
#define WMAX 0.12f
#define SF   ((XMAX / 127.0f) * (WMAX / 127.0f))

typedef __attribute__((ext_vector_type(4))) int i32x4;

__device__ __forceinline__ void load16_to_lds(const void* g, void* l) {
    __builtin_amdgcn_global_load_lds((const __attribute__((address_space(1))) void*)g,
                                     (__attribute__((address_space(3))) void*)l, 16, 0, 0);
}

__device__ __forceinline__ int q127(float v, float inv_step, float vmax) {
    float c = fminf(fmaxf(v, -vmax), vmax);
    return (int)rintf(c * inv_step);
}

// u32 key: top 19 bits = monotone fp32 prefix (floored), low 13 = 8191-col
// (lower col wins ties). key==0 <=> invalid (real keys have low13 >= 3071).
__device__ __forceinline__ int key_col32(unsigned k) { return 8191 - (int)(k & 8191u); }
__device__ __forceinline__ float key_val32(unsigned k) {
    unsigned m = k & 0xFFFFE000u;
    unsigned u = (m & 0x80000000u) ? (m ^ 0x80000000u) : ~m;
    return __uint_as_float(u);
}

// ---------------------------------------------------------------------------
// fused fp32 -> int8 quantize (x clamp +-6, w clamp +-0.12, zero-padded).
// Block 0 also zeroes the rescore job counter (replaces a memset dispatch).
// ---------------------------------------------------------------------------
#define XCNT (M_TOT * H_DIM / 4)
#define WCNT (N_PAD * H_DIM / 4)
__global__ __launch_bounds__(256) void quant_kernel(const float* __restrict__ x,
                                                    const float* __restrict__ gw,
                                                    unsigned* __restrict__ xq,
                                                    unsigned* __restrict__ wq,
                                                    int* __restrict__ counter) {
    if (blockIdx.x == 0 && threadIdx.x == 0) counter[0] = 0;
    const int stride = gridDim.x * blockDim.x;
    const float xinv = 127.0f / XMAX;
    const float winv = 127.0f / WMAX;
    for (int i = blockIdx.x * blockDim.x + threadIdx.x; i < XCNT + WCNT; i += stride) {
        if (i < XCNT) {
            float4 v = ((const float4*)x)[i];
            unsigned p = ((unsigned)(q127(v.x, xinv, XMAX) & 0xff)) |
                         ((unsigned)(q127(v.y, xinv, XMAX) & 0xff) << 8) |
                         ((unsigned)(q127(v.z, xinv, XMAX) & 0xff) << 16) |
                         ((unsigned)(q127(v.w, xinv, XMAX) & 0xff) << 24);
            xq[i] = p;
        } else {
            const int j = i - XCNT;
            const int row = j >> 9;
            unsigned p = 0;
            if (row < NVP1) {
                float4 v = ((const float4*)gw)[j];
                p = ((unsigned)(q127(v.x, winv, WMAX) & 0xff)) |
                    ((unsigned)(q127(v.y, winv, WMAX) & 0xff) << 8) |
                    ((unsigned)(q127(v.z, winv, WMAX) & 0xff) << 16) |
                    ((unsigned)(q127(v.w, winv, WMAX) & 0xff) << 24);
            }
            wq[j] = p;
        }
    }
}

// ---------------------------------------------------------------------------
// int8 MFMA GEMM (xq @ wq^T, exact i32 accum) fused with per-64-col top-3.
// R7/R11-proven loop (single-buffer, __syncthreads, 3 blocks/CU, L2-banded
// XCD mapping, u32-packed keys).
// ---------------------------------------------------------------------------
__global__ __launch_bounds__(256, 3)
void gemm_top3_kernel(const unsigned char* __restrict__ xq,
                      const unsigned char* __restrict__ wq,
                      const float* __restrict__ gb,
                      unsigned* __restrict__ pk1, unsigned* __restrict__ pk2,
                      unsigned* __restrict__ pk3)
{
    __shared__ __align__(16) char albuf[BM * BKB];   // 16 KB, row stride 128B
    __shared__ __align__(16) char blbuf[BN * BKB];   // 16 KB
    __shared__ float bl[BN];

    const int t    = threadIdx.x;
    const int w    = t >> 6;
    const int lane = t & 63;
    const int wm   = w >> 1;
    const int wn   = w & 1;

    // L2-banded XCD mapping: 5120 = 8 xcd * 5 nt * 128 mt
    const int bid0  = blockIdx.x;
    const int xcd   = bid0 & 7;
    const int local = bid0 >> 3;
    const int nt    = xcd * 5 + (local % 5);
    const int mt    = local / 5;
    const int m0    = mt * BM;
    const int n0    = nt * BN;

    if (t < BN) bl[t] = (n0 + t < NVP1) ? gb[n0 + t] : 0.0f;

    const int srow  = lane >> 3;
    const int sslot = lane & 7;
    const char* agp[4];
    const char* bgp[4];
#pragma unroll
    for (int p = 0; p < 4; ++p) {
        const int r = w * 32 + p * 8 + srow;
        agp[p] = (const char*)xq + (size_t)(m0 + r) * H_DIM + ((sslot ^ (r & 7)) << 4);
        bgp[p] = (const char*)wq + (size_t)(n0 + r) * H_DIM + ((sslot ^ (r & 7)) << 4);
    }

    i32x4 acc[4][4];
    const i32x4 z4 = {0, 0, 0, 0};
#pragma unroll
    for (int i = 0; i < 4; ++i)
#pragma unroll
        for (int j = 0; j < 4; ++j) acc[i][j] = z4;

    for (int kt = 0; kt < KITER; ++kt) {
        __syncthreads();
#pragma unroll
        for (int p = 0; p < 4; ++p) {
            load16_to_lds(agp[p] + kt * BKB, albuf + w * 4096 + p * 1024);
            load16_to_lds(bgp[p] + kt * BKB, blbuf + w * 4096 + p * 1024);
        }
        __syncthreads();

#pragma unroll
        for (int kk = 0; kk < 2; ++kk) {
            i32x4 af[4], bfr[4];
#pragma unroll
            for (int f = 0; f < 4; ++f) {
                const int ra = wm * 64 + f * 16 + (lane & 15);
                const int sa = (kk * 4 + (lane >> 4)) ^ (ra & 7);
                af[f] = *(const i32x4*)(albuf + ra * 128 + sa * 16);
                const int rb = wn * 64 + f * 16 + (lane & 15);
                const int sb = (kk * 4 + (lane >> 4)) ^ (rb & 7);
                bfr[f] = *(const i32x4*)(blbuf + rb * 128 + sb * 16);
            }
#pragma unroll
            for (int i = 0; i < 4; ++i)
#pragma unroll
                for (int j = 0; j < 4; ++j)
                    acc[i][j] = __builtin_amdgcn_mfma_i32_16x16x64_i8(af[i], bfr[j], acc[i][j], 0, 0, 0);
        }
    }

    // Epilogue: u32-packed top-3 per row, 16-lane shuffle reduce.
    const int g  = lane >> 4;
    const int cl = lane & 15;
    const int pc = nt * 2 + wn;
#pragma unroll
    for (int fi = 0; fi < 4; ++fi) {
#pragma unroll
        for (int q = 0; q < 4; ++q) {
            unsigned k1 = 0, k2 = 0, k3 = 0;
#pragma unroll
            for (int fj = 0; fj < 4; ++fj) {
                const int cin = wn * 64 + fj * 16 + cl;
                const int col = n0 + cin;
                const float v = (float)acc[fi][fj][q] * SF + bl[cin];
                unsigned u = __float_as_uint(v);
                unsigned mm = u ^ ((u >> 31) ? 0xFFFFFFFFu : 0x80000000u);
                const unsigned k = (col < NVP1)
                    ? ((mm & 0xFFFFE000u) | (8191u - (unsigned)col)) : 0u;
                if (k > k1)      { k3 = k2; k2 = k1; k1 = k; }
                else if (k > k2) { k3 = k2; k2 = k; }
                else if (k > k3) { k3 = k; }
            }
#pragma unroll
            for (int ms = 1; ms < 16; ms <<= 1) {
                const unsigned o1 = __shfl_xor(k1, ms, 64);
                const unsigned o2 = __shfl_xor(k2, ms, 64);
                const unsigned o3 = __shfl_xor(k3, ms, 64);
                const bool a = k1 >= o1;
                const unsigned w2 = a ? k2 : o2, w3 = a ? k3 : o3;
                const unsigned l1 = a ? o1 : k1, l2 = a ? o2 : k2;
                const bool b = w2 >= l1;
                const unsigned n1 = a ? k1 : o1;
                const unsigned n2 = b ? w2 : l1;
                const unsigned n3 = b ? (w3 >= l1 ? w3 : l1) : (w2 >= l2 ? w2 : l2);
                k1 = n1; k2 = n2; k3 = n3;
            }
            if (cl == 0) {
                const int row = m0 + wm * 64 + fi * 16 + g * 4 + q;
                pk1[(size_t)pc * M_TOT + row] = k1;
                pk2[(size_t)pc * M_TOT + row] = k2;
                pk3[(size_t)pc * M_TOT + row] = k3;
            }
        }
    }
}

// ---------------------------------------------------------------------------
// Merge 80 chunk-partials (3 u32 keys each); flag ambiguous tokens.
// ---------------------------------------------------------------------------
__device__ __forceinline__ void ins8k(unsigned k, unsigned tk[8]) {
#pragma unroll
    for (int s = 0; s < 8; ++s) {
        const bool b = k > tk[s];
        const unsigned nv = b ? k : tk[s];
        k = b ? tk[s] : k;
        tk[s] = nv;
    }
}

__global__ __launch_bounds__(256)
void merge_kernel(const unsigned* __restrict__ pk1, const unsigned* __restrict__ pk2,
                  const unsigned* __restrict__ pk3,
                  int* __restrict__ fidx, int* __restrict__ counter, int* __restrict__ jobs)
{
    const int token = blockIdx.x * 256 + threadIdx.x;
    unsigned tk[8];
#pragma unroll
    for (int s = 0; s < 8; ++s) tk[s] = 0;
    for (int pc = 0; pc < NCHUNK; ++pc) {
        ins8k(pk1[(size_t)pc * M_TOT + token], tk);
        ins8k(pk2[(size_t)pc * M_TOT + token], tk);
        ins8k(pk3[(size_t)pc * M_TOT + token], tk);
    }
    const float v0 = key_val32(tk[0]);
    int cols[8];
    int cnt = 0;
#pragma unroll
    for (int s = 0; s < 8; ++s) {
        int c = (tk[s] == 0u) ? 0x7fffffff : key_col32(tk[s]);
        if (c != 0x7fffffff && (unsigned)c > (unsigned)NV) c = 0x7fffffff;
        else if (c != 0x7fffffff && !(key_val32(tk[s]) >= v0 - MARGIN)) c = 0x7fffffff;
        cols[s] = c;
        if (c != 0x7fffffff) cnt++;
    }
    fidx[token] = key_col32(tk[0]);
    if (cnt > 1) {
        const int slot = atomicAdd(counter, 1);
        int* jp = jobs + (size_t)slot * 12;
        jp[0] = token;
        jp[1] = cnt;
#pragma unroll
        for (int s = 0; s < 8; ++s) jp[2 + s] = cols[s];
    }
}

// ---------------------------------------------------------------------------
// Exact fp32 rescore (<=8 dots per flagged token); x-row staged in LDS once.
// ---------------------------------------------------------------------------
__global__ __launch_bounds__(256)
void rescore_kernel(const float* __restrict__ x, const float* __restrict__ gw,
                    const float* __restrict__ gb, const int* __restrict__ jobs,
                    const int* __restrict__ counter, int* __restrict__ fidx)
{
    __shared__ float xl[H_DIM];
    __shared__ float sv[8];
    __shared__ int   si[8];
    __shared__ int   sjob[10];
    const int njobs = counter[0];
    const int t = threadIdx.x;
    for (int j = blockIdx.x; j < njobs; j += gridDim.x) {
        if (t < 10) sjob[t] = jobs[(size_t)j * 12 + t];
        __syncthreads();
        const int token = sjob[0];
        {
            const float4* xr = (const float4*)(x + (size_t)token * H_DIM);
            ((float4*)xl)[t]       = xr[t];
            ((float4*)xl)[t + 256] = xr[t + 256];
        }
        __syncthreads();
        const int g  = t >> 5;
        const int sl = t & 31;
        const int cand = sjob[2 + g];
        float v = -FLT_MAX;
        if (cand <= NV) {
            const float4* wr = (const float4*)(gw + (size_t)cand * H_DIM);
            float s = 0.f;
            for (int k = sl; k < H_DIM / 4; k += 32) {
                const float4 a = ((const float4*)xl)[k];
                const float4 b = wr[k];
                s = fmaf(a.x, b.x, s); s = fmaf(a.y, b.y, s);
                s = fmaf(a.z, b.z, s); s = fmaf(a.w, b.w, s);
            }
#pragma unroll
            for (int m = 1; m < 32; m <<= 1) s += __shfl_xor(s, m, 64);
            v = s + gb[cand];
        }
        if (sl == 0) { sv[g] = v; si[g] = (cand <= NV) ? cand : 0x7fffffff; }
        __syncthreads();
        if (t == 0) {
            float bv = sv[0]; int bi = si[0];
#pragma unroll
            for (int q = 1; q < 8; ++q)
                if (sv[q] > bv || (sv[q] == bv && si[q] < bi)) { bv = sv[q]; bi = si[q]; }
            fidx[token] = bi;
        }
        __syncthreads();
    }
}

// ---------------------------------------------------------------------------
// Final gather
// ---------------------------------------------------------------------------
__global__ __launch_bounds__(256)
void gather_kernel(const float* __restrict__ x, const float* __restrict__ pool,
                   const int* __restrict__ fidx, float* __restrict__ out)
{
    const int token = blockIdx.x;
    const int idx = fidx[token];
    const float4* src;
    if (idx == NV) {
        src = (const float4*)(x + (size_t)token * H_DIM);
    } else {
        const int safe = (idx < NV) ? idx : (NV - 1);
        src = (const float4*)(pool + (size_t)safe * POOL_ROW_STRIDE + POOL_LAYER_OFF);
    }
    float4* dst = (float4*)(out + (size_t)token * H_DIM);
    dst[threadIdx.x]       = src[threadIdx.x];
    dst[threadIdx.x + 256] = src[threadIdx.x + 256];
}

extern "C" void kernel_launch(void* const* d_in, const int* in_sizes, int n_in,
                              void* d_out, int out_size, void* d_ws, size_t ws_size,
                              hipStream_t stream)
{
    const float* x    = (const float*)d_in[0];
    const float* gw   = (const float*)d_in[1];
    const float* gb   = (const float*)d_in[2];
    const float* pool = (const float*)d_in[3];
    float* out = (float*)d_out;

    // x_q parked in d_out (33.5 MB of 134 MB; gather fully overwrites d_out later)
    unsigned char* xq = (unsigned char*)d_out;

    char* wsb = (char*)d_ws;
    unsigned char* wq = (unsigned char*)wsb;                               // 10.5 MB
    size_t off = (size_t)N_PAD * H_DIM;
    unsigned* pk1 = (unsigned*)(wsb + off); off += (size_t)NCHUNK * M_TOT * 4; // 5.24 MB
    unsigned* pk2 = (unsigned*)(wsb + off); off += (size_t)NCHUNK * M_TOT * 4;
    unsigned* pk3 = (unsigned*)(wsb + off); off += (size_t)NCHUNK * M_TOT * 4;
    int* fidx = (int*)(wsb + off); off += (size_t)M_TOT * 4;
    int* counter = (int*)(wsb + off); off += 256;
    int* jobs = (int*)(wsb + off);                                         // 768 KB

    quant_kernel<<<3072, 256, 0, stream>>>(x, gw, (unsigned*)xq, (unsigned*)wq, counter);

    gemm_top3_kernel<<<NWG, 256, 0, stream>>>(xq, wq, gb, pk1, pk2, pk3);

    merge_kernel<<<M_TOT / 256, 256, 0, stream>>>(pk1, pk2, pk3, fidx, counter, jobs);
    rescore_kernel<<<1024, 256, 0, stream>>>(x, gw, gb, jobs, counter, fidx);
    gather_kernel<<<M_TOT, 256, 0, stream>>>(x, pool, fidx, out);
}